// Round 4
// baseline (646.547 us; speedup 1.0000x reference)
//
#include <hip/hip_runtime.h>

// Problem constants: B=64, TQ=1, TK=2048, QD=KD=512, U=1024, H=8, D=128
#define B_   64
#define TK_  2048
#define KD_  512
#define U_   1024
#define H_   8
#define D_   128
#define MT   64
#define APAD 8               // +8 shorts: GEMM reads land conflict-free (bank 4*(l15+lq))
#define ASTR (KD_ + APAD)    // 520 shorts per row
#define NTILE (TK_ / MT)     // 32
#define GRID (B_ * NTILE)    // 2048

typedef float f32x4 __attribute__((ext_vector_type(4)));
typedef short short8 __attribute__((ext_vector_type(8)));

__device__ __forceinline__ short f2bf(float f) {
    unsigned u = __float_as_uint(f);
    u += 0x7fffu + ((u >> 16) & 1u);          // RNE
    return (short)(u >> 16);
}
__device__ __forceinline__ float bf2f(short s) {
    return __uint_as_float(((unsigned)(unsigned short)s) << 16);
}
__device__ __forceinline__ float tanh_fast(float x) {
    float e = __builtin_amdgcn_exp2f(x * 2.885390081777927f);   // exp(2x)
    return 1.0f - 2.0f * __builtin_amdgcn_rcpf(1.0f + e);
}

// Barrier that waits only LDS ops (lgkmcnt(0)); global loads stay in flight.
// Safe: no global-write -> global-read dependency crosses any barrier here.
__device__ __forceinline__ void wg_barrier_lds() {
    asm volatile("" ::: "memory");
    __builtin_amdgcn_s_waitcnt(0xC07F);   // vmcnt(63) expcnt(7) lgkmcnt(0)
    __builtin_amdgcn_s_barrier();
    asm volatile("" ::: "memory");
}

// ---------------- setup kernel 1: normed_v ----------------
__global__ void nv_kernel(const float* __restrict__ v, float* __restrict__ wsNV) {
    __shared__ float red[D_];
    int tid = threadIdx.x;
    float x = v[tid];
    red[tid] = x * x;
    __syncthreads();
    if (tid == 0) {
        float s = 0.f;
        for (int i = 0; i < D_; ++i) s += red[i];
        red[0] = rsqrtf(s) * 0.08838834764831845f;   // 1/sqrt(128)
    }
    __syncthreads();
    wsNV[tid] = x * red[0];
}

// ---------------- setup kernel 2: qb = q.Wq + bq + bk ----------------
__global__ void q_kernel(const float* __restrict__ query, const float* __restrict__ Wq,
                         const float* __restrict__ bq, const float* __restrict__ bk,
                         float* __restrict__ wsQ) {
    __shared__ float qrow[KD_];
    int b = blockIdx.x, ug = blockIdx.y, tid = threadIdx.x;
    if (tid < 128) ((float4*)qrow)[tid] = ((const float4*)(query + (size_t)b * KD_))[tid];
    __syncthreads();
    int u = ug * 256 + tid;
    const float4* wq = (const float4*)(Wq + (size_t)u * KD_);
    const float4* q4 = (const float4*)qrow;
    float acc = 0.f;
#pragma unroll 8
    for (int i = 0; i < KD_ / 4; ++i) {
        float4 a = q4[i], w = wq[i];
        acc += a.x * w.x + a.y * w.y + a.z * w.z + a.w * w.w;
    }
    wsQ[(size_t)b * U_ + u] = acc + bq[u] + bk[u];
}

// ---------------- setup kernel 3: Wk -> fragment-major bf16 ----------------
// frag slot = u_blk*16 + kstep; lane l: u = u_blk*16 + (l&15), k = kstep*32 + (l>>4)*8 + j
__global__ void swz_kernel(const float* __restrict__ Wk, short* __restrict__ wsB) {
    int g = blockIdx.x * 256 + threadIdx.x;   // 0..65535 lane-frags
    int slot = g >> 6, l = g & 63;
    int ublk = slot >> 4, ks = slot & 15;
    int u = ublk * 16 + (l & 15);
    int k0 = ks * 32 + ((l >> 4) << 3);
    const float* src = Wk + (size_t)u * KD_ + k0;
    short8 o;
#pragma unroll
    for (int j = 0; j < 8; ++j) o[j] = f2bf(src[j]);
    *(short8*)(wsB + (size_t)g * 8) = o;
}

// ---------------- main fused kernel ----------------
// 2048 blocks x 512 thr (8 waves); LDS ~68.6 KB -> 2 blocks/CU -> 4 waves/SIMD.
// Wave w owns head w: 2 passes (nh = d-half), nf=4, mf=4 (acc 64 VGPR).
// Split-K staging pipeline: h0 = k[0:256) up front; h1 = k[256:512) written
// after pass0/ks0..7 (HBM latency hidden under GEMM).
template <bool ATOMIC>
__global__ __launch_bounds__(512, 4) void attn_kernel(
    const float* __restrict__ key, const short* __restrict__ wsB,
    const float* __restrict__ wsQ, const float* __restrict__ wsNV,
    float* __restrict__ outp)
{
    __shared__ short As[MT * ASTR];   // 66.6 KB, row-major +8 pad (R2 layout)
    __shared__ float S[MT][H_];
    __shared__ float Wt[MT][H_];

    int bx = blockIdx.x;
    int b = bx & 63, tt = bx >> 6;
    int tid = threadIdx.x;
    int w = tid >> 6, l = tid & 63;
    int l15 = l & 15, lq = l >> 4;

    const float4* kt = (const float4*)(key + ((size_t)b * TK_ + (size_t)tt * MT) * KD_);

    // ---- issue h0 + h1 global loads (8 float4 each per thread, coalesced) ----
    float4 h0v[8], h1v[8];
#pragma unroll
    for (int j = 0; j < 8; ++j) {
        int idx = tid + j * 512;
        h0v[j] = kt[((idx >> 6) << 7) + (idx & 63)];
    }
#pragma unroll
    for (int j = 0; j < 8; ++j) {
        int idx = tid + j * 512;
        h1v[j] = kt[((idx >> 6) << 7) + (idx & 63) + 64];
    }
    // ---- convert + write h0 (waits h0 regs only; h1 stays in flight) ----
#pragma unroll
    for (int j = 0; j < 8; ++j) {
        int idx = tid + j * 512;
        int t = idx >> 6, c4 = (idx & 63) << 2;
        float4 v = h0v[j];
        short4 h4;
        h4.x = f2bf(v.x); h4.y = f2bf(v.y); h4.z = f2bf(v.z); h4.w = f2bf(v.w);
        *(short4*)&As[t * ASTR + c4] = h4;
    }
    wg_barrier_lds();   // barrier A: h0 visible; h1 loads still flying

    const short8* bp = (const short8*)wsB;

    float ps[4][4];
    f32x4 acc[4][4];
    short8 bc[4], bn[4];
    int bbase_cur = 0;

#pragma unroll
    for (int mf = 0; mf < 4; ++mf)
#pragma unroll
        for (int r = 0; r < 4; ++r) ps[mf][r] = 0.f;

    // 2 passes: wave w = head w; nh = pass = d-half. ub = w*128 + nh*64.
    for (int p = 0; p < 2; ++p) {
        int ub = w * 128 + p * 64;
        int bbase = (ub >> 4) * 1024 + l;
        bbase_cur = bbase;

#pragma unroll
        for (int mf = 0; mf < 4; ++mf)
#pragma unroll
            for (int nf = 0; nf < 4; ++nf) acc[mf][nf] = (f32x4){0.f, 0.f, 0.f, 0.f};

        // prefetch score-epilogue operands early (tiny, L2-resident)
        float qv[4], nv[4];
#pragma unroll
        for (int nf = 0; nf < 4; ++nf) {
            qv[nf] = wsQ[(size_t)b * U_ + ub + nf * 16 + l15];
            nv[nf] = wsNV[p * 64 + nf * 16 + l15];
        }

#pragma unroll
        for (int nf = 0; nf < 4; ++nf) bc[nf] = bp[bbase + nf * 1024];

        auto gemm_seg = [&](int ks0, int ks1) {
#pragma unroll 1
            for (int ks = ks0; ks < ks1; ++ks) {
                if (ks < 15) {
#pragma unroll
                    for (int nf = 0; nf < 4; ++nf)
                        bn[nf] = bp[bbase_cur + nf * 1024 + (ks + 1) * 64];
                }
                short8 a[4];
#pragma unroll
                for (int mf = 0; mf < 4; ++mf)
                    a[mf] = *(const short8*)&As[(mf * 16 + l15) * ASTR + ks * 32 + (lq << 3)];
#pragma unroll
                for (int mf = 0; mf < 4; ++mf)
#pragma unroll
                    for (int nf = 0; nf < 4; ++nf)
                        acc[mf][nf] = __builtin_amdgcn_mfma_f32_16x16x32_bf16(
                            a[mf], bc[nf], acc[mf][nf], 0, 0, 0);
                if (ks < 15) {
#pragma unroll
                    for (int nf = 0; nf < 4; ++nf) bc[nf] = bn[nf];
                }
            }
        };

        if (p == 0) {
            gemm_seg(0, 8);                 // consumes h0 (k cols 0..255) while h1 flies
#pragma unroll
            for (int j = 0; j < 8; ++j) {   // convert + write h1
                int idx = tid + j * 512;
                int t = idx >> 6, c4 = ((idx & 63) << 2) + 256;
                float4 v = h1v[j];
                short4 h4;
                h4.x = f2bf(v.x); h4.y = f2bf(v.y); h4.z = f2bf(v.z); h4.w = f2bf(v.w);
                *(short4*)&As[t * ASTR + c4] = h4;
            }
            wg_barrier_lds();               // barrier B: h1 visible
            gemm_seg(8, 16);
        } else {
            gemm_seg(0, 16);
        }

        // ---- score partial: ps += sum_nf nv * tanh(acc + qv) ----
#pragma unroll
        for (int mf = 0; mf < 4; ++mf)
#pragma unroll
            for (int r = 0; r < 4; ++r) {
                float pp = ps[mf][r];
#pragma unroll
                for (int nf = 0; nf < 4; ++nf)
                    pp += nv[nf] * tanh_fast(acc[mf][nf][r] + qv[nf]);
                ps[mf][r] = pp;
            }
        if (p == 1) {
#pragma unroll
            for (int mf = 0; mf < 4; ++mf)
#pragma unroll
                for (int r = 0; r < 4; ++r) {
                    float pp = ps[mf][r];
                    pp += __shfl_xor(pp, 1);
                    pp += __shfl_xor(pp, 2);
                    pp += __shfl_xor(pp, 4);
                    pp += __shfl_xor(pp, 8);
                    // C/D layout: t = mf*16 + lq*4 + r
                    if (l15 == 0) S[mf * 16 + lq * 4 + r][w] = pp;
                }
        }
    }
    wg_barrier_lds();   // barrier C: S complete

    // ---- softmax over heads per t (legacy F.softmax dim=1) ----
    if (tid < MT) {
        float sv[H_];
        float mx = -1e30f;
#pragma unroll
        for (int h = 0; h < H_; ++h) { sv[h] = S[tid][h]; mx = fmaxf(mx, sv[h]); }
        float sum = 0.f;
#pragma unroll
        for (int h = 0; h < H_; ++h) {
            sv[h] = __builtin_amdgcn_exp2f((sv[h] - mx) * 1.4426950408889634f);
            sum += sv[h];
        }
        float inv = __builtin_amdgcn_rcpf(sum);
#pragma unroll
        for (int h = 0; h < H_; ++h) Wt[tid][h] = sv[h] * inv;
    }
    wg_barrier_lds();   // barrier D: Wt complete

    // ---- partial context: 512 thr = (d-group of 4) x (head pair) ----
    int dg = (tid & 127) << 2;        // d in {0,4,...,508}
    int hp = tid >> 7;                // heads 2hp, 2hp+1 (hp in 0..3)
    float cacc[2][4] = {};
#pragma unroll 1
    for (int t = 0; t < MT; ++t) {
        short4 kk = *(const short4*)&As[t * ASTR + dg];
        float k0 = bf2f(kk.x), k1 = bf2f(kk.y), k2 = bf2f(kk.z), k3 = bf2f(kk.w);
        float w0 = Wt[t][2 * hp], w1 = Wt[t][2 * hp + 1];
        cacc[0][0] += w0 * k0; cacc[0][1] += w0 * k1;
        cacc[0][2] += w0 * k2; cacc[0][3] += w0 * k3;
        cacc[1][0] += w1 * k0; cacc[1][1] += w1 * k1;
        cacc[1][2] += w1 * k2; cacc[1][3] += w1 * k3;
    }
    if (ATOMIC) {
        float* ob = outp + (size_t)b * (H_ * KD_);
#pragma unroll
        for (int j = 0; j < 2; ++j)
#pragma unroll
            for (int d = 0; d < 4; ++d)
                atomicAdd(&ob[(2 * hp + j) * KD_ + dg + d], cacc[j][d]);
    } else {
        float* pb = outp + (size_t)bx * (H_ * KD_);
#pragma unroll
        for (int j = 0; j < 2; ++j)
            *(f32x4*)&pb[(2 * hp + j) * KD_ + dg] = *(f32x4*)&cacc[j][0];
    }
}

// ---------------- reduce: out[b][u] = sum_tt partial[tt*64+b][u] ----------------
__global__ void reduce_kernel(const float* __restrict__ partial, float* __restrict__ out) {
    int o = blockIdx.x * 256 + threadIdx.x;   // float4 index, 65536 total
    int b = o >> 10;
    int u4 = o & 1023;
    const f32x4* p4 = (const f32x4*)partial;
    f32x4 s = {0.f, 0.f, 0.f, 0.f};
#pragma unroll 8
    for (int tt = 0; tt < NTILE; ++tt)
        s += p4[((size_t)(tt * 64 + b)) * 1024 + u4];
    ((f32x4*)out)[o] = s;
}

extern "C" void kernel_launch(void* const* d_in, const int* in_sizes, int n_in,
                              void* d_out, int out_size, void* d_ws, size_t ws_size,
                              hipStream_t stream) {
    const float* query = (const float*)d_in[0];
    const float* key   = (const float*)d_in[1];
    const float* Wq    = (const float*)d_in[2];
    const float* bq    = (const float*)d_in[3];
    const float* Wk    = (const float*)d_in[4];
    const float* bk    = (const float*)d_in[5];
    const float* v     = (const float*)d_in[6];
    float* out = (float*)d_out;

    char* ws = (char*)d_ws;
    float* wsNV = (float*)ws;                       // 512 B
    float* wsQ  = (float*)(ws + 4096);              // 256 KB
    short* wsB  = (short*)(ws + 524288);            // 1 MB swizzled bf16 Wk
    float* wsP  = (float*)(ws + 2 * 1024 * 1024);   // 33.55 MB partial contexts

    size_t need = 2 * 1024 * 1024 + (size_t)GRID * (H_ * KD_) * sizeof(float);

    nv_kernel<<<1, 128, 0, stream>>>(v, wsNV);
    q_kernel<<<dim3(64, 4), 256, 0, stream>>>(query, Wq, bq, bk, wsQ);
    swz_kernel<<<256, 256, 0, stream>>>(Wk, wsB);

    if (ws_size >= need) {
        attn_kernel<false><<<GRID, 512, 0, stream>>>(key, wsB, wsQ, wsNV, wsP);
        reduce_kernel<<<256, 256, 0, stream>>>(wsP, out);
    } else {
        hipMemsetAsync(d_out, 0, (size_t)out_size * sizeof(float), stream);
        attn_kernel<true><<<GRID, 512, 0, stream>>>(key, wsB, wsQ, wsNV, out);
    }
}

// Round 5
// 529.581 us; speedup vs baseline: 1.2209x; 1.2209x over previous
//
#include <hip/hip_runtime.h>

// Problem constants: B=64, TQ=1, TK=2048, QD=KD=512, U=1024, H=8, D=128
#define B_   64
#define TK_  2048
#define KD_  512
#define U_   1024
#define H_   8
#define D_   128
#define MT   64
#define APAD 8               // +8 shorts pad (R2-proven layout; conflicts measured benign)
#define ASTR (KD_ + APAD)    // 520 shorts per row
#define NTILE (TK_ / MT)     // 32
#define GRID (B_ * NTILE)    // 2048

typedef float f32x4 __attribute__((ext_vector_type(4)));
typedef short short8 __attribute__((ext_vector_type(8)));

__device__ __forceinline__ short f2bf(float f) {
    unsigned u = __float_as_uint(f);
    u += 0x7fffu + ((u >> 16) & 1u);          // RNE
    return (short)(u >> 16);
}
__device__ __forceinline__ float bf2f(short s) {
    return __uint_as_float(((unsigned)(unsigned short)s) << 16);
}
__device__ __forceinline__ float tanh_fast(float x) {
    float e = __builtin_amdgcn_exp2f(x * 2.885390081777927f);   // exp(2x)
    return 1.0f - 2.0f * __builtin_amdgcn_rcpf(1.0f + e);
}

// Barrier waiting only LDS ops; global loads (B prefetch) stay in flight.
__device__ __forceinline__ void wg_barrier_lds() {
    asm volatile("" ::: "memory");
    __builtin_amdgcn_s_waitcnt(0xC07F);   // vmcnt(63) expcnt(7) lgkmcnt(0)
    __builtin_amdgcn_s_barrier();
    asm volatile("" ::: "memory");
}

// ---------------- setup kernel 1: normed_v ----------------
__global__ void nv_kernel(const float* __restrict__ v, float* __restrict__ wsNV) {
    __shared__ float red[D_];
    int tid = threadIdx.x;
    float x = v[tid];
    red[tid] = x * x;
    __syncthreads();
    if (tid == 0) {
        float s = 0.f;
        for (int i = 0; i < D_; ++i) s += red[i];
        red[0] = rsqrtf(s) * 0.08838834764831845f;   // 1/sqrt(128)
    }
    __syncthreads();
    wsNV[tid] = x * red[0];
}

// ---------------- setup kernel 2: qb = q.Wq + bq + bk ----------------
__global__ void q_kernel(const float* __restrict__ query, const float* __restrict__ Wq,
                         const float* __restrict__ bq, const float* __restrict__ bk,
                         float* __restrict__ wsQ) {
    __shared__ float qrow[KD_];
    int b = blockIdx.x, ug = blockIdx.y, tid = threadIdx.x;
    if (tid < 128) ((float4*)qrow)[tid] = ((const float4*)(query + (size_t)b * KD_))[tid];
    __syncthreads();
    int u = ug * 256 + tid;
    const float4* wq = (const float4*)(Wq + (size_t)u * KD_);
    const float4* q4 = (const float4*)qrow;
    float acc = 0.f;
#pragma unroll 8
    for (int i = 0; i < KD_ / 4; ++i) {
        float4 a = q4[i], w = wq[i];
        acc += a.x * w.x + a.y * w.y + a.z * w.z + a.w * w.w;
    }
    wsQ[(size_t)b * U_ + u] = acc + bq[u] + bk[u];
}

// ---------------- setup kernel 3: Wk -> fragment-major bf16 ----------------
// frag slot = u_blk*16 + kstep; lane l: u = u_blk*16 + (l&15), k = kstep*32 + (l>>4)*8 + j
__global__ void swz_kernel(const float* __restrict__ Wk, short* __restrict__ wsB) {
    int g = blockIdx.x * 256 + threadIdx.x;   // 0..65535 lane-frags
    int slot = g >> 6, l = g & 63;
    int ublk = slot >> 4, ks = slot & 15;
    int u = ublk * 16 + (l & 15);
    int k0 = ks * 32 + ((l >> 4) << 3);
    const float* src = Wk + (size_t)u * KD_ + k0;
    short8 o;
#pragma unroll
    for (int j = 0; j < 8; ++j) o[j] = f2bf(src[j]);
    *(short8*)(wsB + (size_t)g * 8) = o;
}

// ---------------- main fused kernel ----------------
// 2048 blocks x 512 thr (8 waves). __launch_bounds__(512,2): 2nd arg is
// min BLOCKS/CU (CUDA semantics — R4 evidence: (512,4) capped VGPRs at 64
// = 2048/32 waves, causing catastrophic spills). (512,2) -> 16 waves/CU
// -> 128-reg cap -> 4 waves/SIMD with LDS ~72.7 KB x 2 blocks.
// Wave w = head w; 2 passes p (d-half); nf=4, mf=4 (acc 64 VGPR).
template <bool ATOMIC>
__global__ __launch_bounds__(512, 2) void attn_kernel(
    const float* __restrict__ key, const short* __restrict__ wsB,
    const float* __restrict__ wsQ, const float* __restrict__ wsNV,
    float* __restrict__ outp)
{
    __shared__ short As[MT * ASTR];   // 66.6 KB bf16 tile (GEMM-A + value)
    __shared__ float S[MT][16];       // per-(head,d-half) score partials
    __shared__ float Wt[MT][H_];

    int bx = blockIdx.x;
    int b = bx & 63, tt = bx >> 6;
    int tid = threadIdx.x;
    int w = tid >> 6, l = tid & 63;
    int l15 = l & 15, lq = l >> 4;

    const float4* kt = (const float4*)(key + ((size_t)b * TK_ + (size_t)tt * MT) * KD_);

    // ---- stage 64x512 fp32 -> bf16 LDS in 2 rounds of 8 float4/thread ----
#pragma unroll
    for (int r = 0; r < 2; ++r) {
        float4 hv[8];
#pragma unroll
        for (int j = 0; j < 8; ++j) {
            int idx = tid + j * 512;
            hv[j] = kt[((idx >> 6) << 7) + (idx & 63) + r * 64];
        }
#pragma unroll
        for (int j = 0; j < 8; ++j) {
            int idx = tid + j * 512;
            int t = idx >> 6, c4 = ((idx & 63) << 2) + r * 256;
            float4 v = hv[j];
            short4 h4;
            h4.x = f2bf(v.x); h4.y = f2bf(v.y); h4.z = f2bf(v.z); h4.w = f2bf(v.w);
            *(short4*)&As[t * ASTR + c4] = h4;
        }
    }
    wg_barrier_lds();   // tile visible

    const short8* bp = (const short8*)wsB;
    f32x4 acc[4][4];
    short8 bc[4];

    // 2 passes: wave w = head w; p = d-half. ub = w*128 + p*64.
#pragma unroll 1
    for (int p = 0; p < 2; ++p) {
        int ub = w * 128 + p * 64;
        int bbase = (ub >> 4) * 1024 + l;

#pragma unroll
        for (int mf = 0; mf < 4; ++mf)
#pragma unroll
            for (int nf = 0; nf < 4; ++nf) acc[mf][nf] = (f32x4){0.f, 0.f, 0.f, 0.f};

#pragma unroll
        for (int nf = 0; nf < 4; ++nf) bc[nf] = bp[bbase + nf * 1024];

#pragma unroll 1
        for (int ks = 0; ks < 16; ++ks) {
            short8 bn[4];
            if (ks < 15) {
#pragma unroll
                for (int nf = 0; nf < 4; ++nf)
                    bn[nf] = bp[bbase + nf * 1024 + (ks + 1) * 64];
            }
            short8 a[4];
#pragma unroll
            for (int mf = 0; mf < 4; ++mf)
                a[mf] = *(const short8*)&As[(mf * 16 + l15) * ASTR + ks * 32 + (lq << 3)];
#pragma unroll
            for (int mf = 0; mf < 4; ++mf)
#pragma unroll
                for (int nf = 0; nf < 4; ++nf)
                    acc[mf][nf] = __builtin_amdgcn_mfma_f32_16x16x32_bf16(
                        a[mf], bc[nf], acc[mf][nf], 0, 0, 0);
            if (ks < 15) {
#pragma unroll
                for (int nf = 0; nf < 4; ++nf) bc[nf] = bn[nf];
            }
        }

        // ---- score partial for this (head, d-half): write S[t][w*2+p] ----
        float qv[4], nv[4];
#pragma unroll
        for (int nf = 0; nf < 4; ++nf) {
            qv[nf] = wsQ[(size_t)b * U_ + ub + nf * 16 + l15];
            nv[nf] = wsNV[p * 64 + nf * 16 + l15];
        }
#pragma unroll
        for (int mf = 0; mf < 4; ++mf)
#pragma unroll
            for (int r = 0; r < 4; ++r) {
                float pp = 0.f;
#pragma unroll
                for (int nf = 0; nf < 4; ++nf)
                    pp += nv[nf] * tanh_fast(acc[mf][nf][r] + qv[nf]);
                pp += __shfl_xor(pp, 1);
                pp += __shfl_xor(pp, 2);
                pp += __shfl_xor(pp, 4);
                pp += __shfl_xor(pp, 8);
                // C/D layout: t = mf*16 + lq*4 + r
                if (l15 == 0) S[mf * 16 + lq * 4 + r][w * 2 + p] = pp;
            }
    }
    wg_barrier_lds();   // S complete

    // ---- softmax over heads per t (legacy F.softmax dim=1) ----
    if (tid < MT) {
        float sv[H_];
        float mx = -1e30f;
#pragma unroll
        for (int h = 0; h < H_; ++h) {
            sv[h] = S[tid][2 * h] + S[tid][2 * h + 1];
            mx = fmaxf(mx, sv[h]);
        }
        float sum = 0.f;
#pragma unroll
        for (int h = 0; h < H_; ++h) {
            sv[h] = __builtin_amdgcn_exp2f((sv[h] - mx) * 1.4426950408889634f);
            sum += sv[h];
        }
        float inv = __builtin_amdgcn_rcpf(sum);
#pragma unroll
        for (int h = 0; h < H_; ++h) Wt[tid][h] = sv[h] * inv;
    }
    wg_barrier_lds();   // Wt complete

    // ---- partial context: 512 thr = (d-group of 4) x (head pair) ----
    int dg = (tid & 127) << 2;        // d in {0,4,...,508}
    int hp = tid >> 7;                // heads 2hp, 2hp+1
    float cacc[2][4] = {};
#pragma unroll 1
    for (int t = 0; t < MT; ++t) {
        short4 kk = *(const short4*)&As[t * ASTR + dg];
        float k0 = bf2f(kk.x), k1 = bf2f(kk.y), k2 = bf2f(kk.z), k3 = bf2f(kk.w);
        float w0 = Wt[t][2 * hp], w1 = Wt[t][2 * hp + 1];
        cacc[0][0] += w0 * k0; cacc[0][1] += w0 * k1;
        cacc[0][2] += w0 * k2; cacc[0][3] += w0 * k3;
        cacc[1][0] += w1 * k0; cacc[1][1] += w1 * k1;
        cacc[1][2] += w1 * k2; cacc[1][3] += w1 * k3;
    }
    if (ATOMIC) {
        float* ob = outp + (size_t)b * (H_ * KD_);
#pragma unroll
        for (int j = 0; j < 2; ++j)
#pragma unroll
            for (int d = 0; d < 4; ++d)
                atomicAdd(&ob[(2 * hp + j) * KD_ + dg + d], cacc[j][d]);
    } else {
        float* pb = outp + (size_t)bx * (H_ * KD_);
#pragma unroll
        for (int j = 0; j < 2; ++j)
            *(f32x4*)&pb[(2 * hp + j) * KD_ + dg] = *(f32x4*)&cacc[j][0];
    }
}

// ---------------- reduce: out[b][u] = sum_tt partial[tt*64+b][u] ----------------
__global__ void reduce_kernel(const float* __restrict__ partial, float* __restrict__ out) {
    int o = blockIdx.x * 256 + threadIdx.x;   // float4 index, 65536 total
    int b = o >> 10;
    int u4 = o & 1023;
    const f32x4* p4 = (const f32x4*)partial;
    f32x4 s = {0.f, 0.f, 0.f, 0.f};
#pragma unroll 8
    for (int tt = 0; tt < NTILE; ++tt)
        s += p4[((size_t)(tt * 64 + b)) * 1024 + u4];
    ((f32x4*)out)[o] = s;
}

extern "C" void kernel_launch(void* const* d_in, const int* in_sizes, int n_in,
                              void* d_out, int out_size, void* d_ws, size_t ws_size,
                              hipStream_t stream) {
    const float* query = (const float*)d_in[0];
    const float* key   = (const float*)d_in[1];
    const float* Wq    = (const float*)d_in[2];
    const float* bq    = (const float*)d_in[3];
    const float* Wk    = (const float*)d_in[4];
    const float* bk    = (const float*)d_in[5];
    const float* v     = (const float*)d_in[6];
    float* out = (float*)d_out;

    char* ws = (char*)d_ws;
    float* wsNV = (float*)ws;                       // 512 B
    float* wsQ  = (float*)(ws + 4096);              // 256 KB
    short* wsB  = (short*)(ws + 524288);            // 1 MB swizzled bf16 Wk
    float* wsP  = (float*)(ws + 2 * 1024 * 1024);   // 33.55 MB partial contexts

    size_t need = 2 * 1024 * 1024 + (size_t)GRID * (H_ * KD_) * sizeof(float);

    nv_kernel<<<1, 128, 0, stream>>>(v, wsNV);
    q_kernel<<<dim3(64, 4), 256, 0, stream>>>(query, Wq, bq, bk, wsQ);
    swz_kernel<<<256, 256, 0, stream>>>(Wk, wsB);

    if (ws_size >= need) {
        attn_kernel<false><<<GRID, 512, 0, stream>>>(key, wsB, wsQ, wsNV, wsP);
        reduce_kernel<<<256, 256, 0, stream>>>(wsP, out);
    } else {
        hipMemsetAsync(d_out, 0, (size_t)out_size * sizeof(float), stream);
        attn_kernel<true><<<GRID, 512, 0, stream>>>(key, wsB, wsQ, wsNV, out);
    }
}